// Round 11
// baseline (149.102 us; speedup 1.0000x reference)
//
#include <hip/hip_runtime.h>

// ---------------------------------------------------------------------------
// SelfAttention with QA-LoRA quantized projections, MI355X (gfx950)
// Round 11: GEMM = round-9 counted-vmcnt schedule + B-operand loaded DIRECT
//           to registers (per-lane 16B fragment loads from L2-hot W panels;
//           no B LDS, no B ds_read). A stays global_load_lds + XOR swizzle,
//           double-buffered (32KB). Attn / prep / T1 unchanged.
// ---------------------------------------------------------------------------

typedef __bf16 bf16x8 __attribute__((ext_vector_type(8)));
typedef float f32x4 __attribute__((ext_vector_type(4)));

#define MFMA(a, b, c) __builtin_amdgcn_mfma_f32_16x16x32_bf16(a, b, c, 0, 0, 0)

#define KEXT 1088   // 1024 + 64 extension cols (16 LoRA + 48 zeros)

__device__ __forceinline__ void gld16(const void* g, void* l) {
  __builtin_amdgcn_global_load_lds(
      (const __attribute__((address_space(1))) void*)g,
      (__attribute__((address_space(3))) void*)l, 16, 0, 0);
}

// fake_quantize: returns the clipped, round-half-even INTEGER (not dequantized).
__device__ __forceinline__ float fq(float v) {
  float q = rintf(v / 0.1f);           // v_rndne_f32: round half to even
  return fminf(fmaxf(q, -128.f), 127.f);
}

__device__ __forceinline__ float redsum16(float v) {
  v += __shfl_xor(v, 1);
  v += __shfl_xor(v, 2);
  v += __shfl_xor(v, 4);
  v += __shfl_xor(v, 8);
  return v;
}

// ---------------- prep kernels ----------------

// weights -> bf16 int codes into stride-1088 layout
__global__ __launch_bounds__(256) void k_quant_w(
    const float* __restrict__ w0, const float* __restrict__ w1,
    const float* __restrict__ w2, const float* __restrict__ w3,
    __bf16* __restrict__ wq) {
  int i = blockIdx.x * 256 + threadIdx.x;          // 4 * 1024 * 256
  int layer = i >> 18, rest = i & 262143;
  int o = rest >> 8, c4 = rest & 255;
  const float* src = (layer == 0) ? w0 : (layer == 1) ? w1 : (layer == 2) ? w2 : w3;
  float4 v = ((const float4*)src)[rest];
  __bf16 r[4] = {(__bf16)fq(v.x), (__bf16)fq(v.y), (__bf16)fq(v.z), (__bf16)fq(v.w)};
  *(uint2*)(wq + (size_t)((layer << 10) | o) * KEXT + (c4 << 2)) = *(uint2*)r;
}

// fused: x fp32 -> bf16 (stride 1088) AND extension cols = group means.
__global__ __launch_bounds__(256) void k_xprep(const float* __restrict__ x,
                                               __bf16* __restrict__ xbf) {
  int row = blockIdx.x, t = threadIdx.x;
  float4 v = ((const float4*)(x + (size_t)row * 1024))[t];
  __bf16 r[4] = {(__bf16)v.x, (__bf16)v.y, (__bf16)v.z, (__bf16)v.w};
  *(uint2*)(xbf + (size_t)row * KEXT + 4 * t) = *(uint2*)r;
  float s = v.x + v.y + v.z + v.w;
  s = redsum16(s);                                  // all 16 lanes of group hold sum
  int g = t >> 4, j = t & 15;
  __bf16* ext = xbf + (size_t)row * KEXT + 1024;
  if (j == 0) ext[g] = (__bf16)(s * (1.f / 64.f));
  else if (j < 4) ext[16 + g * 3 + (j - 1)] = (__bf16)0.f;   // zero cols 1040..1087
}

// LoRA delta -> extension cols of wq: wq_ext[o][g] = bf16(20 * dBq@dWq * 0.01)
__global__ __launch_bounds__(256) void k_delta(
    const float* __restrict__ dW0, const float* __restrict__ dB0,
    const float* __restrict__ dW1, const float* __restrict__ dB1,
    const float* __restrict__ dW2, const float* __restrict__ dB2,
    const float* __restrict__ dW3, const float* __restrict__ dB3,
    __bf16* __restrict__ wq) {
  int i = blockIdx.x * 256 + threadIdx.x;          // 65536 = 4*1024*16
  int layer = i >> 14, o = (i >> 4) & 1023, g = i & 15;
  const float* dW = (layer == 0) ? dW0 : (layer == 1) ? dW1 : (layer == 2) ? dW2 : dW3;
  const float* dB = (layer == 0) ? dB0 : (layer == 1) ? dB1 : (layer == 2) ? dB2 : dB3;
  float acc = 0.f;
#pragma unroll
  for (int r = 0; r < 32; ++r)
    acc += (0.1f * fq(dB[o * 32 + r])) * (0.1f * fq(dW[r * 16 + g]));
  __bf16* ext = wq + (size_t)((layer << 10) | o) * KEXT + 1024;
  ext[g] = (__bf16)(20.f * acc);
#pragma unroll
  for (int k = 0; k < 3; ++k) ext[16 + g * 3 + k] = (__bf16)0.f;
}

// ---------------- GEMM (A: LDS dbuf+swizzle; B: direct-to-reg; T4; T1) ------
// y = 0.1 * (A_ext @ W_ext^T) over K'=1088; 128x128 tile, BK=64, 4 waves.
// mode 0: 1D grid of 768 = {bm 32} x {zn 24 = z*8+bn}; XCD rect = 8bm x 12zn.
// mode 1: 1D grid of 256 = {bm 32} x {bn 8}; XCD rect = 8bm x 4bn; fp32 out.
__global__ __launch_bounds__(256) void k_gemm(
    const __bf16* __restrict__ A,       // [4096][1088]
    const __bf16* __restrict__ Wq,      // [4][1024][1088]
    __bf16* __restrict__ qout,          // [bh][n][64]
    __bf16* __restrict__ kout,          // [bh][n][64]
    __bf16* __restrict__ vout,          // [bh][64][n] (sigma-permuted n)
    float* __restrict__ fout,           // [4096][1024]
    int mode, int layer_base) {
  __shared__ __align__(16) __bf16 lA[2][128 * 64];   // A tiles only (32KB)

  const int t = threadIdx.x;
  const int lane = t & 63;
  const int wv = t >> 6;

  // T1: XCD-rectangle decode
  int bm, bn, z;
  {
    int xcd = blockIdx.x & 7, local = blockIdx.x >> 3;
    if (mode == 0) {                     // 768 blocks: local 0..95 = 8bm x 12zn
      int bm_l = local / 12, zn_l = local - bm_l * 12;
      bm = ((xcd >> 1) << 3) + bm_l;
      int zn = (xcd & 1) * 12 + zn_l;
      z = zn >> 3;
      bn = zn & 7;
    } else {                             // 256 blocks: local 0..31 = 8bm x 4bn
      int bm_l = local >> 2, bn_l = local & 3;
      bm = ((xcd >> 1) << 3) + bm_l;
      bn = (xcd & 1) * 4 + bn_l;
      z = 0;
    }
  }
  const int layer = layer_base + z;
  const __bf16* Wl = Wq + (size_t)layer * 1024 * KEXT;
  const int wm = wv >> 1, wn = wv & 1;
  const int fr = lane & 15, fq4 = lane >> 4;

  const int tr = t >> 3;                      // row within 32-row group
  const int scol = ((t & 7) ^ (tr & 7)) * 8;  // swizzled element offset (A)

  // per-lane B fragment base: row = bn*128 + wn*64 + ni*16 + fr
  const __bf16* Wrow = Wl + (size_t)(bn * 128 + wn * 64 + fr) * KEXT + fq4 * 8;

  f32x4 acc[4][4];
#pragma unroll
  for (int mi = 0; mi < 4; ++mi)
#pragma unroll
    for (int ni = 0; ni < 4; ++ni) { f32x4 zz = {0.f, 0.f, 0.f, 0.f}; acc[mi][ni] = zz; }

  bf16x8 b0[8], b1[8];   // named ping-pong B fragment sets (rule #20)

#define STAGE_A(kt, buf)                                                       \
  {                                                                            \
    _Pragma("unroll") for (int i = 0; i < 4; ++i) {                            \
      int row = i * 32 + tr;                                                   \
      gld16(A + (size_t)(bm * 128 + row) * KEXT + (kt)*64 + scol,              \
            (char*)lA[buf] + (i * 256 + wv * 64) * 16);                        \
    }                                                                          \
  }
#define LOADB(kt, BR)                                                          \
  {                                                                            \
    _Pragma("unroll") for (int kk = 0; kk < 2; ++kk)                           \
        _Pragma("unroll") for (int ni = 0; ni < 4; ++ni)                       \
            BR[kk * 4 + ni] = *(const bf16x8*)(Wrow + (size_t)(ni * 16) * KEXT + \
                                               (kt)*64 + kk * 32);             \
  }
#define KCOMPUTE(CUR, BR)                                                      \
  {                                                                            \
    _Pragma("unroll") for (int kk = 0; kk < 2; ++kk) {                         \
      bf16x8 af[4];                                                            \
      _Pragma("unroll") for (int mi = 0; mi < 4; ++mi)                         \
        af[mi] = *(const bf16x8*)&lA[CUR][(wm * 64 + mi * 16 + fr) * 64 +      \
                                          (((kk << 2) | fq4) ^ (fr & 7)) * 8]; \
      _Pragma("unroll") for (int mi = 0; mi < 4; ++mi)                         \
        _Pragma("unroll") for (int ni = 0; ni < 4; ++ni)                       \
            acc[mi][ni] = MFMA(af[mi], BR[kk * 4 + ni], acc[mi][ni]);          \
    }                                                                          \
  }

  STAGE_A(0, 0);
  LOADB(0, b0);
  // tiles 0..15 in 8 unrolled iterations (tile kt uses lA[kt&1]); tile 16 peeled.
  // Each tile issues next tile's 12 loads (4 A-gld16 + 8 B-reg), then waits
  // vmcnt(12): current tile's loads done, next tile's stay in flight across
  // both barriers (T4).
  for (int it = 0; it < 8; ++it) {
    int e = it * 2;
    // ---- even tile e (A buf 0, B regs b0) ----
    STAGE_A(e + 1, 1);
    LOADB(e + 1, b1);
    asm volatile("s_waitcnt vmcnt(12)" ::: "memory");
    __builtin_amdgcn_s_barrier();
    __builtin_amdgcn_sched_barrier(0);
    __builtin_amdgcn_s_setprio(1);
    KCOMPUTE(0, b0);
    __builtin_amdgcn_s_setprio(0);
    __builtin_amdgcn_sched_barrier(0);
    __builtin_amdgcn_s_barrier();
    // ---- odd tile e+1 (A buf 1, B regs b1) ----
    STAGE_A(e + 2, 0);
    LOADB(e + 2, b0);
    asm volatile("s_waitcnt vmcnt(12)" ::: "memory");
    __builtin_amdgcn_s_barrier();
    __builtin_amdgcn_sched_barrier(0);
    __builtin_amdgcn_s_setprio(1);
    KCOMPUTE(1, b1);
    __builtin_amdgcn_s_setprio(0);
    __builtin_amdgcn_sched_barrier(0);
    __builtin_amdgcn_s_barrier();
  }
  // ---- tail tile 16 (A buf 0, B regs b0) ----
  asm volatile("s_waitcnt vmcnt(0)" ::: "memory");
  __builtin_amdgcn_s_barrier();
  __builtin_amdgcn_sched_barrier(0);
  KCOMPUTE(0, b0);
  __syncthreads();   // full drain before epilogue LDS reuse
#undef STAGE_A
#undef LOADB
#undef KCOMPUTE

  // q scale folds 0.1 (dequant), 1/sqrt(64), log2(e) for log2-domain softmax
  const float outmul =
      (mode == 0 && z == 0) ? 0.1f * 0.125f * 1.4426950408889634f : 0.1f;

  if (mode == 0 && z == 2) {
    // --- V^T epilogue: repack via LDS (32KB dead after final barrier) -------
    __bf16* lw = ((__bf16*)lA) + wv * 4096;   // 8KB wave-private
#pragma unroll
    for (int mi = 0; mi < 4; ++mi) {
      int cc = mi * 2 + (fq4 >> 1), qq = fq4 & 1;
      int sb = (((cc & 4) | (qq << 1) | (cc & 1)) << 3) | ((cc & 2) << 1);
      int lc = sb >> 3, half = (sb >> 2) & 1;
#pragma unroll
      for (int ni = 0; ni < 4; ++ni) {
        int d = ni * 16 + fr;
        __bf16 pk[4];
#pragma unroll
        for (int j = 0; j < 4; ++j) pk[j] = (__bf16)(acc[mi][ni][j] * outmul);
        *(uint2*)&lw[d * 64 + ((lc ^ (d & 7)) << 3) + half * 4] = *(uint2*)pk;
      }
    }
    // same-wave DS ordering: writes visible to own reads, no barrier
    int d = lane;
    int m0 = bm * 128 + wm * 64;
    int b = m0 >> 11, n0 = m0 & 2047;
    int h = bn * 2 + wn;
    __bf16* vrow = vout + ((size_t)(b * 16 + h) * 64 + d) * 2048 + n0;
#pragma unroll
    for (int lc2 = 0; lc2 < 8; ++lc2) {
      uint4 val = *(uint4*)&lw[d * 64 + ((lc2 ^ (d & 7)) << 3)];
      *(uint4*)(vrow + lc2 * 8) = val;
    }
  } else {
#pragma unroll
    for (int mi = 0; mi < 4; ++mi)
#pragma unroll
      for (int ni = 0; ni < 4; ++ni) {
        int o = bn * 128 + wn * 64 + ni * 16 + fr;
#pragma unroll
        for (int j = 0; j < 4; ++j) {
          int m = bm * 128 + wm * 64 + mi * 16 + fq4 * 4 + j;
          float v = acc[mi][ni][j] * outmul;
          if (mode == 0) {
            int b = m >> 11, nr = m & 2047;
            int h = o >> 6, d = o & 63;
            if (z == 0)
              qout[((size_t)(b * 16 + h) * 2048 + nr) * 64 + d] = (__bf16)v;
            else
              kout[((size_t)(b * 16 + h) * 2048 + nr) * 64 + d] = (__bf16)v;
          } else {
            fout[(size_t)m * 1024 + o] = v;
          }
        }
      }
  }
}

// ---------------- flash attention (round 9 structure, unchanged) ------------
__global__ __launch_bounds__(256) void k_attn(
    const __bf16* __restrict__ qb,   // [bh][n][64] (pre-scaled, log2 domain)
    const __bf16* __restrict__ kb,   // [bh][n][64]
    const __bf16* __restrict__ vbt,  // [bh][64][n] (sigma-permuted n)
    __bf16* __restrict__ attnb) {    // [4096][1088] (ext cols = head means)
  __shared__ __align__(16) __bf16 lK[2][64 * 64];
  __shared__ __align__(16) __bf16 lVT[2][64 * 64];

  const int t = threadIdx.x, lane = t & 63, wv = t >> 6;
  // T1: XCD rect = 4bh x 16qt -> each bh's K/V fetched by one XCD only
  const int xcd = blockIdx.x & 7, local = blockIdx.x >> 3;   // local 0..63
  const int bh = xcd * 4 + (local >> 4);
  const int qt = local & 15;                   // 0..15 (128 q-rows per block)
  const int fr = lane & 15, g = lane >> 4;
  const int qrow0 = qt * 128 + wv * 16;
  const size_t hbase = (size_t)bh * 2048 * 64;

  const int srow0 = t >> 3, sc0 = (t & 7) ^ (srow0 & 7);
  const int srow1 = (256 + t) >> 3, sc1 = (t & 7) ^ (srow1 & 7);
  const int dst0 = (wv * 64) * 16, dst1 = (256 + wv * 64) * 16;

  bf16x8 qf[2][2];
#pragma unroll
  for (int s = 0; s < 2; ++s)
#pragma unroll
    for (int kk = 0; kk < 2; ++kk)
      qf[s][kk] = *(const bf16x8*)(qb + hbase + (size_t)(qrow0 + s * 64 + fr) * 64 +
                                   kk * 32 + g * 8);

  bf16x8 vones;
#pragma unroll
  for (int e = 0; e < 8; ++e) vones[e] = (__bf16)1.0f;

  f32x4 o[2][4], o4[2];
#pragma unroll
  for (int s = 0; s < 2; ++s) {
#pragma unroll
    for (int di = 0; di < 4; ++di) { f32x4 zz = {0.f, 0.f, 0.f, 0.f}; o[s][di] = zz; }
    f32x4 zz = {0.f, 0.f, 0.f, 0.f};
    o4[s] = zz;
  }

  f32x4 smA[2][4], smB[2][4];

#define SK_STAGE(KT, BUF)                                                      \
  {                                                                            \
    int kn = (KT)*64;                                                          \
    gld16(kb + hbase + (size_t)(kn + srow0) * 64 + sc0 * 8, (char*)(BUF) + dst0); \
    gld16(kb + hbase + (size_t)(kn + srow1) * 64 + sc1 * 8, (char*)(BUF) + dst1); \
  }
#define SV_STAGE(KT, BUF)                                                      \
  {                                                                            \
    int kn = (KT)*64;                                                          \
    gld16(vbt + hbase + (size_t)srow0 * 2048 + kn + sc0 * 8, (char*)(BUF) + dst0); \
    gld16(vbt + hbase + (size_t)srow1 * 2048 + kn + sc1 * 8, (char*)(BUF) + dst1); \
  }
#define QK_STEP(KBUF, SM)                                                      \
  {                                                                            \
    _Pragma("unroll") for (int ni = 0; ni < 4; ++ni) {                         \
      f32x4 zz = {0.f, 0.f, 0.f, 0.f};                                         \
      SM[0][ni] = zz;                                                          \
      SM[1][ni] = zz;                                                          \
    }                                                                          \
    _Pragma("unroll") for (int kk = 0; kk < 2; ++kk)                           \
        _Pragma("unroll") for (int ni = 0; ni < 4; ++ni) {                     \
      bf16x8 kf = *(const bf16x8*)&(KBUF)[(ni * 16 + fr) * 64 +                \
                                          (((kk << 2) | g) ^ (fr & 7)) * 8];   \
      SM[0][ni] = MFMA(kf, qf[0][kk], SM[0][ni]);                              \
      SM[1][ni] = MFMA(kf, qf[1][kk], SM[1][ni]);                              \
    }                                                                          \
  }
#define EXPPV_STEP(SM, VBUF)                                                   \
  {                                                                            \
    bf16x8 pa[2][2];                                                           \
    _Pragma("unroll") for (int s2 = 0; s2 < 2; ++s2)                           \
        _Pragma("unroll") for (int kk = 0; kk < 2; ++kk)                       \
            _Pragma("unroll") for (int e = 0; e < 8; ++e)                      \
                pa[s2][kk][e] = (__bf16)__builtin_amdgcn_exp2f(                \
                    SM[s2][2 * kk + (e >> 2)][e & 3]);                         \
    _Pragma("unroll") for (int kk = 0; kk < 2; ++kk) {                         \
      const int ncr = ((kk << 2) | ((g & 1) << 1) | (g >> 1)) ^ (fr & 7);      \
      _Pragma("unroll") for (int di = 0; di < 4; ++di) {                       \
        bf16x8 vf = *(const bf16x8*)&(VBUF)[(di * 16 + fr) * 64 + ncr * 8];    \
        o[0][di] = MFMA(pa[0][kk], vf, o[0][di]);                              \
        o[1][di] = MFMA(pa[1][kk], vf, o[1][di]);                              \
      }                                                                        \
      o4[0] = MFMA(pa[0][kk], vones, o4[0]);                                   \
      o4[1] = MFMA(pa[1][kk], vones, o4[1]);                                   \
    }                                                                          \
  }
#define WAITBAR(N)                                                             \
  asm volatile("s_waitcnt vmcnt(" #N ")" ::: "memory");                        \
  __builtin_amdgcn_s_barrier();                                                \
  __builtin_amdgcn_sched_barrier(0);
#define ENDBAR                                                                 \
  __builtin_amdgcn_sched_barrier(0);                                           \
  __builtin_amdgcn_s_barrier();

  // prologue: K(0) staged (2 loads in flight)
  SK_STAGE(0, lK[0]);

  for (int it = 0; it < 15; ++it) {
    int t2 = it * 2;
    // ---- even half: tile t2 ----
    SK_STAGE(t2 + 1, lK[1]);
    SV_STAGE(t2, lVT[0]);
    WAITBAR(4)                       // prev-odd's 4 (K(t2),V(t2-1)) done
    __builtin_amdgcn_s_setprio(1);
    QK_STEP(lK[0], smB);
    if (it > 0) { EXPPV_STEP(smA, lVT[1]); }
    __builtin_amdgcn_s_setprio(0);
    ENDBAR
    // ---- odd half: tile t2+1 ----
    SK_STAGE(t2 + 2, lK[0]);
    SV_STAGE(t2 + 1, lVT[1]);
    WAITBAR(4)                       // even's 4 (K(t2+1),V(t2)) done
    __builtin_amdgcn_s_setprio(1);
    QK_STEP(lK[1], smA);
    EXPPV_STEP(smB, lVT[0]);
    __builtin_amdgcn_s_setprio(0);
    ENDBAR
  }
  // ---- peeled it=15: tiles 30, 31 ----
  SK_STAGE(31, lK[1]);
  SV_STAGE(30, lVT[0]);
  WAITBAR(4)
  __builtin_amdgcn_s_setprio(1);
  QK_STEP(lK[0], smB);
  EXPPV_STEP(smA, lVT[1]);           // S(29), V(29)
  __builtin_amdgcn_s_setprio(0);
  ENDBAR
  SV_STAGE(31, lVT[1]);
  WAITBAR(2)                         // even's 4 done (2 newer = V(31))
  __builtin_amdgcn_s_setprio(1);
  QK_STEP(lK[1], smA);
  EXPPV_STEP(smB, lVT[0]);           // S(30), V(30)
  __builtin_amdgcn_s_setprio(0);
  ENDBAR
  WAITBAR(0)                         // V(31) done
  EXPPV_STEP(smA, lVT[1]);           // S(31), V(31)

#undef SK_STAGE
#undef SV_STAGE
#undef QK_STEP
#undef EXPPV_STEP
#undef WAITBAR
#undef ENDBAR

  // epilogue: normalize, write attn bf16 into stride-1088 rows + ext cols
  const int b = bh >> 4, h = bh & 15;
#pragma unroll
  for (int s = 0; s < 2; ++s)
#pragma unroll
    for (int j = 0; j < 4; ++j) {
      float inv = 1.f / o4[s][j];
      int nr = qt * 128 + s * 64 + wv * 16 + g * 4 + j;
      size_t rowbase = (size_t)(b * 2048 + nr) * KEXT;
      float rowsum = 0.f;
#pragma unroll
      for (int di = 0; di < 4; ++di) {
        float vv = o[s][di][j] * inv;
        attnb[rowbase + h * 64 + di * 16 + fr] = (__bf16)vv;
        rowsum += vv;
      }
      rowsum = redsum16(rowsum);
      if (fr == 0) attnb[rowbase + 1024 + h] = (__bf16)(rowsum * (1.f / 64.f));
      if (h < 3) attnb[rowbase + 1040 + h * 16 + fr] = (__bf16)0.f;  // zero pad
    }
}

// ---------------- launch ----------------
extern "C" void kernel_launch(void* const* d_in, const int* in_sizes, int n_in,
                              void* d_out, int out_size, void* d_ws, size_t ws_size,
                              hipStream_t stream) {
  const float* x = (const float*)d_in[0];
  const float* w_[4]  = {(const float*)d_in[1], (const float*)d_in[4],
                         (const float*)d_in[7], (const float*)d_in[10]};
  const float* dW_[4] = {(const float*)d_in[2], (const float*)d_in[5],
                         (const float*)d_in[8], (const float*)d_in[11]};
  const float* dB_[4] = {(const float*)d_in[3], (const float*)d_in[6],
                         (const float*)d_in[9], (const float*)d_in[12]};
  float* out = (float*)d_out;

  char* ws = (char*)d_ws;
  const size_t MB = 1ull << 20;
  __bf16* xbf   = (__bf16*)(ws);                 // 4096*1088*2 = 8.9 MB
  __bf16* attnb = xbf;                           // alias: xbf dead after QKV GEMM
  __bf16* wq    = (__bf16*)(ws + 9 * MB);        // 4*1024*1088*2 = 8.9 MB
  __bf16* qb    = (__bf16*)(ws + 18 * MB);       // 8 MB
  __bf16* kb    = (__bf16*)(ws + 26 * MB);       // 8 MB
  __bf16* vbt   = (__bf16*)(ws + 34 * MB);       // 8 MB -> ends 42 MB

  k_quant_w<<<4096, 256, 0, stream>>>(w_[0], w_[1], w_[2], w_[3], wq);
  k_xprep<<<4096, 256, 0, stream>>>(x, xbf);
  k_delta<<<256, 256, 0, stream>>>(dW_[0], dB_[0], dW_[1], dB_[1],
                                   dW_[2], dB_[2], dW_[3], dB_[3], wq);
  k_gemm<<<768, 256, 0, stream>>>(xbf, wq, qb, kb, vbt, nullptr, 0, 0);
  k_attn<<<512, 256, 0, stream>>>(qb, kb, vbt, attnb);
  k_gemm<<<256, 256, 0, stream>>>(attnb, wq, nullptr, nullptr, nullptr,
                                  out, 1, 3);
}

// Round 12
// 113.130 us; speedup vs baseline: 1.3180x; 1.3180x over previous
//
#include <hip/hip_runtime.h>

// ---------------------------------------------------------------------------
// SelfAttention with QA-LoRA quantized projections, MI355X (gfx950)
// Round 12: round-9 GEMM schedule restored (counted-vmcnt, A+B LDS dbuf,
//           XOR swizzle, K-ext, T1) but with 512-thread blocks: 8 waves
//           (2x4), wave tile 64x32, acc[4][2]. Same 64KB LDS -> still
//           2 blocks/CU but 16 waves/CU (was 8): doubles TLP for the
//           latency-bound loop. Attn / prep identical to round 9.
// ---------------------------------------------------------------------------

typedef __bf16 bf16x8 __attribute__((ext_vector_type(8)));
typedef float f32x4 __attribute__((ext_vector_type(4)));

#define MFMA(a, b, c) __builtin_amdgcn_mfma_f32_16x16x32_bf16(a, b, c, 0, 0, 0)

#define KEXT 1088   // 1024 + 64 extension cols (16 LoRA + 48 zeros)

__device__ __forceinline__ void gld16(const void* g, void* l) {
  __builtin_amdgcn_global_load_lds(
      (const __attribute__((address_space(1))) void*)g,
      (__attribute__((address_space(3))) void*)l, 16, 0, 0);
}

// fake_quantize: returns the clipped, round-half-even INTEGER (not dequantized).
__device__ __forceinline__ float fq(float v) {
  float q = rintf(v / 0.1f);           // v_rndne_f32: round half to even
  return fminf(fmaxf(q, -128.f), 127.f);
}

__device__ __forceinline__ float redsum16(float v) {
  v += __shfl_xor(v, 1);
  v += __shfl_xor(v, 2);
  v += __shfl_xor(v, 4);
  v += __shfl_xor(v, 8);
  return v;
}

// ---------------- prep kernels ----------------

// weights -> bf16 int codes into stride-1088 layout
__global__ __launch_bounds__(256) void k_quant_w(
    const float* __restrict__ w0, const float* __restrict__ w1,
    const float* __restrict__ w2, const float* __restrict__ w3,
    __bf16* __restrict__ wq) {
  int i = blockIdx.x * 256 + threadIdx.x;          // 4 * 1024 * 256
  int layer = i >> 18, rest = i & 262143;
  int o = rest >> 8, c4 = rest & 255;
  const float* src = (layer == 0) ? w0 : (layer == 1) ? w1 : (layer == 2) ? w2 : w3;
  float4 v = ((const float4*)src)[rest];
  __bf16 r[4] = {(__bf16)fq(v.x), (__bf16)fq(v.y), (__bf16)fq(v.z), (__bf16)fq(v.w)};
  *(uint2*)(wq + (size_t)((layer << 10) | o) * KEXT + (c4 << 2)) = *(uint2*)r;
}

// fused: x fp32 -> bf16 (stride 1088) AND extension cols = group means.
__global__ __launch_bounds__(256) void k_xprep(const float* __restrict__ x,
                                               __bf16* __restrict__ xbf) {
  int row = blockIdx.x, t = threadIdx.x;
  float4 v = ((const float4*)(x + (size_t)row * 1024))[t];
  __bf16 r[4] = {(__bf16)v.x, (__bf16)v.y, (__bf16)v.z, (__bf16)v.w};
  *(uint2*)(xbf + (size_t)row * KEXT + 4 * t) = *(uint2*)r;
  float s = v.x + v.y + v.z + v.w;
  s = redsum16(s);                                  // all 16 lanes of group hold sum
  int g = t >> 4, j = t & 15;
  __bf16* ext = xbf + (size_t)row * KEXT + 1024;
  if (j == 0) ext[g] = (__bf16)(s * (1.f / 64.f));
  else if (j < 4) ext[16 + g * 3 + (j - 1)] = (__bf16)0.f;   // zero cols 1040..1087
}

// LoRA delta -> extension cols of wq: wq_ext[o][g] = bf16(20 * dBq@dWq * 0.01)
__global__ __launch_bounds__(256) void k_delta(
    const float* __restrict__ dW0, const float* __restrict__ dB0,
    const float* __restrict__ dW1, const float* __restrict__ dB1,
    const float* __restrict__ dW2, const float* __restrict__ dB2,
    const float* __restrict__ dW3, const float* __restrict__ dB3,
    __bf16* __restrict__ wq) {
  int i = blockIdx.x * 256 + threadIdx.x;          // 65536 = 4*1024*16
  int layer = i >> 14, o = (i >> 4) & 1023, g = i & 15;
  const float* dW = (layer == 0) ? dW0 : (layer == 1) ? dW1 : (layer == 2) ? dW2 : dW3;
  const float* dB = (layer == 0) ? dB0 : (layer == 1) ? dB1 : (layer == 2) ? dB2 : dB3;
  float acc = 0.f;
#pragma unroll
  for (int r = 0; r < 32; ++r)
    acc += (0.1f * fq(dB[o * 32 + r])) * (0.1f * fq(dW[r * 16 + g]));
  __bf16* ext = wq + (size_t)((layer << 10) | o) * KEXT + 1024;
  ext[g] = (__bf16)(20.f * acc);
#pragma unroll
  for (int k = 0; k < 3; ++k) ext[16 + g * 3 + k] = (__bf16)0.f;
}

// ---------------- GEMM (8-wave, counted-vmcnt dbuf + swizzle + K-ext + T1) --
// y = 0.1 * (A_ext @ W_ext^T) over K'=1088; 128x128 tile, BK=64, 8 waves
// (2x4), wave tile 64x32, acc[4][2]. 64KB LDS -> 2 blocks/CU, 16 waves/CU.
// mode 0: 1D grid of 768 = {bm 32} x {zn 24 = z*8+bn}; XCD rect = 8bm x 12zn.
// mode 1: 1D grid of 256 = {bm 32} x {bn 8}; XCD rect = 8bm x 4bn; fp32 out.
__global__ __launch_bounds__(512) void k_gemm(
    const __bf16* __restrict__ A,       // [4096][1088]
    const __bf16* __restrict__ Wq,      // [4][1024][1088]
    __bf16* __restrict__ qout,          // [bh][n][64]
    __bf16* __restrict__ kout,          // [bh][n][64]
    __bf16* __restrict__ vout,          // [bh][64][n] (sigma-permuted n)
    float* __restrict__ fout,           // [4096][1024]
    int mode, int layer_base) {
  __shared__ __align__(16) __bf16 lA[2][128 * 64];
  __shared__ __align__(16) __bf16 lB[2][128 * 64];

  const int t = threadIdx.x;           // 0..511
  const int lane = t & 63;
  const int wv = t >> 6;               // 0..7

  // T1: XCD-rectangle decode
  int bm, bn, z;
  {
    int xcd = blockIdx.x & 7, local = blockIdx.x >> 3;
    if (mode == 0) {                     // 768 blocks: local 0..95 = 8bm x 12zn
      int bm_l = local / 12, zn_l = local - bm_l * 12;
      bm = ((xcd >> 1) << 3) + bm_l;
      int zn = (xcd & 1) * 12 + zn_l;
      z = zn >> 3;
      bn = zn & 7;
    } else {                             // 256 blocks: local 0..31 = 8bm x 4bn
      int bm_l = local >> 2, bn_l = local & 3;
      bm = ((xcd >> 1) << 3) + bm_l;
      bn = (xcd & 1) * 4 + bn_l;
      z = 0;
    }
  }
  const int layer = layer_base + z;
  const __bf16* Wl = Wq + (size_t)layer * 1024 * KEXT;
  const int wm = wv >> 2, wn = wv & 3;   // 2 x 4 wave grid
  const int fr = lane & 15, fq4 = lane >> 4;

  const int tr = t >> 3;                      // 0..63: row within 64-row group
  const int scol = ((t & 7) ^ (tr & 7)) * 8;  // swizzled element offset

  f32x4 acc[4][2];
#pragma unroll
  for (int mi = 0; mi < 4; ++mi)
#pragma unroll
    for (int ni = 0; ni < 2; ++ni) { f32x4 zz = {0.f, 0.f, 0.f, 0.f}; acc[mi][ni] = zz; }

#define STAGE(kt, buf)                                                         \
  {                                                                            \
    _Pragma("unroll") for (int i = 0; i < 2; ++i) {                            \
      int row = i * 64 + tr;                                                   \
      gld16(A + (size_t)(bm * 128 + row) * KEXT + (kt)*64 + scol,              \
            (char*)lA[buf] + (i * 512 + wv * 64) * 16);                        \
      gld16(Wl + (size_t)(bn * 128 + row) * KEXT + (kt)*64 + scol,             \
            (char*)lB[buf] + (i * 512 + wv * 64) * 16);                        \
    }                                                                          \
  }
#define KCOMPUTE(CUR)                                                          \
  {                                                                            \
    _Pragma("unroll") for (int kk = 0; kk < 2; ++kk) {                         \
      bf16x8 af[4], bfr[2];                                                    \
      _Pragma("unroll") for (int mi = 0; mi < 4; ++mi)                         \
        af[mi] = *(const bf16x8*)&lA[CUR][(wm * 64 + mi * 16 + fr) * 64 +      \
                                          (((kk << 2) | fq4) ^ (fr & 7)) * 8]; \
      _Pragma("unroll") for (int ni = 0; ni < 2; ++ni)                         \
        bfr[ni] = *(const bf16x8*)&lB[CUR][(wn * 32 + ni * 16 + fr) * 64 +     \
                                           (((kk << 2) | fq4) ^ (fr & 7)) * 8];\
      _Pragma("unroll") for (int mi = 0; mi < 4; ++mi)                         \
        _Pragma("unroll") for (int ni = 0; ni < 2; ++ni)                       \
            acc[mi][ni] = MFMA(af[mi], bfr[ni], acc[mi][ni]);                  \
    }                                                                          \
  }

  STAGE(0, 0);
  int cur = 0;
  // Counted-vmcnt 2-barrier schedule: tile kt+1's 4 loads stay in flight
  // across both barriers and land under tile kt's MFMAs (T4).
  for (int kt = 0; kt < 16; ++kt) {
    STAGE(kt + 1, cur ^ 1);
    asm volatile("s_waitcnt vmcnt(4)" ::: "memory");   // tile kt's loads done
    __builtin_amdgcn_s_barrier();
    __builtin_amdgcn_sched_barrier(0);
    __builtin_amdgcn_s_setprio(1);
    KCOMPUTE(cur);
    __builtin_amdgcn_s_setprio(0);
    __builtin_amdgcn_sched_barrier(0);
    __builtin_amdgcn_s_barrier();                      // buf[cur] free
    cur ^= 1;
  }
  // tail: tile 16 (LoRA extension tile)
  asm volatile("s_waitcnt vmcnt(0)" ::: "memory");
  __builtin_amdgcn_s_barrier();
  __builtin_amdgcn_sched_barrier(0);
  KCOMPUTE(cur);
  __syncthreads();   // full drain before epilogue LDS reuse
#undef STAGE
#undef KCOMPUTE

  // q scale folds 0.1 (dequant), 1/sqrt(64), log2(e) for log2-domain softmax
  const float outmul =
      (mode == 0 && z == 0) ? 0.1f * 0.125f * 1.4426950408889634f : 0.1f;

  if (mode == 0 && z == 2) {
    // --- V^T epilogue: repack via LDS (dead after final barrier) ------------
    // Wave tile = 64 rows (n, full sigma group) x 32 cols (d).
    // h = bn*2 + (wn>>1); global d = (wn&1)*32 + d_local.
    __bf16* lw = ((__bf16*)lA) + wv * 2048;   // 4KB wave-private (8x4KB=32KB)
#pragma unroll
    for (int mi = 0; mi < 4; ++mi) {
      int cc = mi * 2 + (fq4 >> 1), qq = fq4 & 1;
      int sb = (((cc & 4) | (qq << 1) | (cc & 1)) << 3) | ((cc & 2) << 1);
      int lc = sb >> 3, half = (sb >> 2) & 1;
#pragma unroll
      for (int ni = 0; ni < 2; ++ni) {
        int dl = ni * 16 + fr;               // 0..31
        __bf16 pk[4];
#pragma unroll
        for (int j = 0; j < 4; ++j) pk[j] = (__bf16)(acc[mi][ni][j] * outmul);
        *(uint2*)&lw[dl * 64 + ((lc ^ (dl & 7)) << 3) + half * 4] = *(uint2*)pk;
      }
    }
    // same-wave DS ordering: writes visible to own reads, no barrier
    int dl = lane >> 1, c0 = (lane & 1) * 4;
    int m0 = bm * 128 + wm * 64;
    int b = m0 >> 11, n0 = m0 & 2047;
    int h = bn * 2 + (wn >> 1);
    int dg = (wn & 1) * 32 + dl;
    __bf16* vrow = vout + ((size_t)(b * 16 + h) * 64 + dg) * 2048 + n0;
#pragma unroll
    for (int lc2 = 0; lc2 < 4; ++lc2) {
      int c = c0 + lc2;
      uint4 val = *(uint4*)&lw[dl * 64 + ((c ^ (dl & 7)) << 3)];
      *(uint4*)(vrow + c * 8) = val;
    }
  } else {
#pragma unroll
    for (int mi = 0; mi < 4; ++mi)
#pragma unroll
      for (int ni = 0; ni < 2; ++ni) {
        int o = bn * 128 + wn * 32 + ni * 16 + fr;
#pragma unroll
        for (int j = 0; j < 4; ++j) {
          int m = bm * 128 + wm * 64 + mi * 16 + fq4 * 4 + j;
          float v = acc[mi][ni][j] * outmul;
          if (mode == 0) {
            int b = m >> 11, nr = m & 2047;
            int h = o >> 6, d = o & 63;
            if (z == 0)
              qout[((size_t)(b * 16 + h) * 2048 + nr) * 64 + d] = (__bf16)v;
            else
              kout[((size_t)(b * 16 + h) * 2048 + nr) * 64 + d] = (__bf16)v;
          } else {
            fout[(size_t)m * 1024 + o] = v;
          }
        }
      }
  }
}

// ---------------- flash attention (round 9 structure, unchanged) ------------
__global__ __launch_bounds__(256) void k_attn(
    const __bf16* __restrict__ qb,   // [bh][n][64] (pre-scaled, log2 domain)
    const __bf16* __restrict__ kb,   // [bh][n][64]
    const __bf16* __restrict__ vbt,  // [bh][64][n] (sigma-permuted n)
    __bf16* __restrict__ attnb) {    // [4096][1088] (ext cols = head means)
  __shared__ __align__(16) __bf16 lK[2][64 * 64];
  __shared__ __align__(16) __bf16 lVT[2][64 * 64];

  const int t = threadIdx.x, lane = t & 63, wv = t >> 6;
  // T1: XCD rect = 4bh x 16qt -> each bh's K/V fetched by one XCD only
  const int xcd = blockIdx.x & 7, local = blockIdx.x >> 3;   // local 0..63
  const int bh = xcd * 4 + (local >> 4);
  const int qt = local & 15;                   // 0..15 (128 q-rows per block)
  const int fr = lane & 15, g = lane >> 4;
  const int qrow0 = qt * 128 + wv * 16;
  const size_t hbase = (size_t)bh * 2048 * 64;

  const int srow0 = t >> 3, sc0 = (t & 7) ^ (srow0 & 7);
  const int srow1 = (256 + t) >> 3, sc1 = (t & 7) ^ (srow1 & 7);
  const int dst0 = (wv * 64) * 16, dst1 = (256 + wv * 64) * 16;

  bf16x8 qf[2][2];
#pragma unroll
  for (int s = 0; s < 2; ++s)
#pragma unroll
    for (int kk = 0; kk < 2; ++kk)
      qf[s][kk] = *(const bf16x8*)(qb + hbase + (size_t)(qrow0 + s * 64 + fr) * 64 +
                                   kk * 32 + g * 8);

  bf16x8 vones;
#pragma unroll
  for (int e = 0; e < 8; ++e) vones[e] = (__bf16)1.0f;

  f32x4 o[2][4], o4[2];
#pragma unroll
  for (int s = 0; s < 2; ++s) {
#pragma unroll
    for (int di = 0; di < 4; ++di) { f32x4 zz = {0.f, 0.f, 0.f, 0.f}; o[s][di] = zz; }
    f32x4 zz = {0.f, 0.f, 0.f, 0.f};
    o4[s] = zz;
  }

  f32x4 smA[2][4], smB[2][4];

#define SK_STAGE(KT, BUF)                                                      \
  {                                                                            \
    int kn = (KT)*64;                                                          \
    gld16(kb + hbase + (size_t)(kn + srow0) * 64 + sc0 * 8, (char*)(BUF) + dst0); \
    gld16(kb + hbase + (size_t)(kn + srow1) * 64 + sc1 * 8, (char*)(BUF) + dst1); \
  }
#define SV_STAGE(KT, BUF)                                                      \
  {                                                                            \
    int kn = (KT)*64;                                                          \
    gld16(vbt + hbase + (size_t)srow0 * 2048 + kn + sc0 * 8, (char*)(BUF) + dst0); \
    gld16(vbt + hbase + (size_t)srow1 * 2048 + kn + sc1 * 8, (char*)(BUF) + dst1); \
  }
#define QK_STEP(KBUF, SM)                                                      \
  {                                                                            \
    _Pragma("unroll") for (int ni = 0; ni < 4; ++ni) {                         \
      f32x4 zz = {0.f, 0.f, 0.f, 0.f};                                         \
      SM[0][ni] = zz;                                                          \
      SM[1][ni] = zz;                                                          \
    }                                                                          \
    _Pragma("unroll") for (int kk = 0; kk < 2; ++kk)                           \
        _Pragma("unroll") for (int ni = 0; ni < 4; ++ni) {                     \
      bf16x8 kf = *(const bf16x8*)&(KBUF)[(ni * 16 + fr) * 64 +                \
                                          (((kk << 2) | g) ^ (fr & 7)) * 8];   \
      SM[0][ni] = MFMA(kf, qf[0][kk], SM[0][ni]);                              \
      SM[1][ni] = MFMA(kf, qf[1][kk], SM[1][ni]);                              \
    }                                                                          \
  }
#define EXPPV_STEP(SM, VBUF)                                                   \
  {                                                                            \
    bf16x8 pa[2][2];                                                           \
    _Pragma("unroll") for (int s2 = 0; s2 < 2; ++s2)                           \
        _Pragma("unroll") for (int kk = 0; kk < 2; ++kk)                       \
            _Pragma("unroll") for (int e = 0; e < 8; ++e)                      \
                pa[s2][kk][e] = (__bf16)__builtin_amdgcn_exp2f(                \
                    SM[s2][2 * kk + (e >> 2)][e & 3]);                         \
    _Pragma("unroll") for (int kk = 0; kk < 2; ++kk) {                         \
      const int ncr = ((kk << 2) | ((g & 1) << 1) | (g >> 1)) ^ (fr & 7);      \
      _Pragma("unroll") for (int di = 0; di < 4; ++di) {                       \
        bf16x8 vf = *(const bf16x8*)&(VBUF)[(di * 16 + fr) * 64 + ncr * 8];    \
        o[0][di] = MFMA(pa[0][kk], vf, o[0][di]);                              \
        o[1][di] = MFMA(pa[1][kk], vf, o[1][di]);                              \
      }                                                                        \
      o4[0] = MFMA(pa[0][kk], vones, o4[0]);                                   \
      o4[1] = MFMA(pa[1][kk], vones, o4[1]);                                   \
    }                                                                          \
  }
#define WAITBAR(N)                                                             \
  asm volatile("s_waitcnt vmcnt(" #N ")" ::: "memory");                        \
  __builtin_amdgcn_s_barrier();                                                \
  __builtin_amdgcn_sched_barrier(0);
#define ENDBAR                                                                 \
  __builtin_amdgcn_sched_barrier(0);                                           \
  __builtin_amdgcn_s_barrier();

  // prologue: K(0) staged (2 loads in flight)
  SK_STAGE(0, lK[0]);

  for (int it = 0; it < 15; ++it) {
    int t2 = it * 2;
    // ---- even half: tile t2 ----
    SK_STAGE(t2 + 1, lK[1]);
    SV_STAGE(t2, lVT[0]);
    WAITBAR(4)                       // prev-odd's 4 (K(t2),V(t2-1)) done
    __builtin_amdgcn_s_setprio(1);
    QK_STEP(lK[0], smB);
    if (it > 0) { EXPPV_STEP(smA, lVT[1]); }
    __builtin_amdgcn_s_setprio(0);
    ENDBAR
    // ---- odd half: tile t2+1 ----
    SK_STAGE(t2 + 2, lK[0]);
    SV_STAGE(t2 + 1, lVT[1]);
    WAITBAR(4)                       // even's 4 (K(t2+1),V(t2)) done
    __builtin_amdgcn_s_setprio(1);
    QK_STEP(lK[1], smA);
    EXPPV_STEP(smB, lVT[0]);
    __builtin_amdgcn_s_setprio(0);
    ENDBAR
  }
  // ---- peeled it=15: tiles 30, 31 ----
  SK_STAGE(31, lK[1]);
  SV_STAGE(30, lVT[0]);
  WAITBAR(4)
  __builtin_amdgcn_s_setprio(1);
  QK_STEP(lK[0], smB);
  EXPPV_STEP(smA, lVT[1]);           // S(29), V(29)
  __builtin_amdgcn_s_setprio(0);
  ENDBAR
  SV_STAGE(31, lVT[1]);
  WAITBAR(2)                         // even's 4 done (2 newer = V(31))
  __builtin_amdgcn_s_setprio(1);
  QK_STEP(lK[1], smA);
  EXPPV_STEP(smB, lVT[0]);           // S(30), V(30)
  __builtin_amdgcn_s_setprio(0);
  ENDBAR
  WAITBAR(0)                         // V(31) done
  EXPPV_STEP(smA, lVT[1]);           // S(31), V(31)

#undef SK_STAGE
#undef SV_STAGE
#undef QK_STEP
#undef EXPPV_STEP
#undef WAITBAR
#undef ENDBAR

  // epilogue: normalize, write attn bf16 into stride-1088 rows + ext cols
  const int b = bh >> 4, h = bh & 15;
#pragma unroll
  for (int s = 0; s < 2; ++s)
#pragma unroll
    for (int j = 0; j < 4; ++j) {
      float inv = 1.f / o4[s][j];
      int nr = qt * 128 + s * 64 + wv * 16 + g * 4 + j;
      size_t rowbase = (size_t)(b * 2048 + nr) * KEXT;
      float rowsum = 0.f;
#pragma unroll
      for (int di = 0; di < 4; ++di) {
        float vv = o[s][di][j] * inv;
        attnb[rowbase + h * 64 + di * 16 + fr] = (__bf16)vv;
        rowsum += vv;
      }
      rowsum = redsum16(rowsum);
      if (fr == 0) attnb[rowbase + 1024 + h] = (__bf16)(rowsum * (1.f / 64.f));
      if (h < 3) attnb[rowbase + 1040 + h * 16 + fr] = (__bf16)0.f;  // zero pad
    }
}

// ---------------- launch ----------------
extern "C" void kernel_launch(void* const* d_in, const int* in_sizes, int n_in,
                              void* d_out, int out_size, void* d_ws, size_t ws_size,
                              hipStream_t stream) {
  const float* x = (const float*)d_in[0];
  const float* w_[4]  = {(const float*)d_in[1], (const float*)d_in[4],
                         (const float*)d_in[7], (const float*)d_in[10]};
  const float* dW_[4] = {(const float*)d_in[2], (const float*)d_in[5],
                         (const float*)d_in[8], (const float*)d_in[11]};
  const float* dB_[4] = {(const float*)d_in[3], (const float*)d_in[6],
                         (const float*)d_in[9], (const float*)d_in[12]};
  float* out = (float*)d_out;

  char* ws = (char*)d_ws;
  const size_t MB = 1ull << 20;
  __bf16* xbf   = (__bf16*)(ws);                 // 4096*1088*2 = 8.9 MB
  __bf16* attnb = xbf;                           // alias: xbf dead after QKV GEMM
  __bf16* wq    = (__bf16*)(ws + 9 * MB);        // 4*1024*1088*2 = 8.9 MB
  __bf16* qb    = (__bf16*)(ws + 18 * MB);       // 8 MB
  __bf16* kb    = (__bf16*)(ws + 26 * MB);       // 8 MB
  __bf16* vbt   = (__bf16*)(ws + 34 * MB);       // 8 MB -> ends 42 MB

  k_quant_w<<<4096, 256, 0, stream>>>(w_[0], w_[1], w_[2], w_[3], wq);
  k_xprep<<<4096, 256, 0, stream>>>(x, xbf);
  k_delta<<<256, 256, 0, stream>>>(dW_[0], dB_[0], dW_[1], dB_[1],
                                   dW_[2], dB_[2], dW_[3], dB_[3], wq);
  k_gemm<<<768, 512, 0, stream>>>(xbf, wq, qb, kb, vbt, nullptr, 0, 0);
  k_attn<<<512, 256, 0, stream>>>(qb, kb, vbt, attnb);
  k_gemm<<<256, 512, 0, stream>>>(attnb, wq, nullptr, nullptr, nullptr,
                                  out, 1, 3);
}